// Round 1
// baseline (6325.434 us; speedup 1.0000x reference)
//
#include <hip/hip_runtime.h>
#include <hip/hip_bf16.h>

#define Bsz 32
#define Tn  64
#define Vn  32000
#define En  300
#define Hn  512
#define NFn 128
#define Dn  32
#define G4  2048
#define LIN 332

// workspace offsets (float units)
#define OFF_MPROJ 0
#define OFF_MKEY  (OFF_MPROJ + Bsz*NFn*Dn)          /* 131072   */
#define OFF_E0    (OFF_MKEY + Bsz*NFn*Hn)           /* 2228224  */
#define OFF_PG0   (OFF_E0 + Tn*G4*Bsz)              /* 6422528  */
#define OFF_H1T   (OFF_PG0 + G4*Bsz)
#define OFF_C1T   (OFF_H1T + Hn*Bsz)
#define OFF_C2T   (OFF_C1T + Hn*Bsz)
#define OFF_H2A   (OFF_C2T + Hn*Bsz)
#define OFF_H2B   (OFF_H2A + Hn*Bsz)
#define OFF_HBF   (OFF_H2B + Hn*Bsz)                /* bf16 [2048][512] */
#define OFF_FCWBF (OFF_HBF + (2048*512)/2)          /* bf16 [32000][512] */

// output offsets (float units)
#define OUT_HF  65536000
#define OUT_CF  65568768
#define OUT_ATT 65601536

typedef __attribute__((ext_vector_type(8))) short short8;
typedef __attribute__((ext_vector_type(4))) float f32x4;
typedef unsigned short u16;

__device__ __forceinline__ float frcp(float x){ return __builtin_amdgcn_rcpf(x); }
__device__ __forceinline__ float ftanh(float x){
  float e = __expf(2.0f*x);
  return 1.0f - 2.0f*frcp(e+1.0f);
}
__device__ __forceinline__ float fsig(float x){
  return frcp(1.0f + __expf(-x));
}
__device__ __forceinline__ u16 f2bf(float f){
  __hip_bfloat16 h = __float2bfloat16(f);
  u16 r; __builtin_memcpy(&r, &h, 2); return r;
}

// ---------------- P1: midi_proj + midi_key ----------------
__global__ __launch_bounds__(1024) void p1_midi(
    const float* __restrict__ midi, const float* __restrict__ mp_w,
    const float* __restrict__ mp_b, const float* __restrict__ wm,
    float* __restrict__ ws)
{
  __shared__ float ms[NFn*Dn];
  __shared__ float pj[NFn*Dn];
  __shared__ float mpw[Dn*33];
  __shared__ float mpb[Dn];
  int b = blockIdx.x, tid = threadIdx.x;
  for (int i=tid;i<NFn*Dn;i+=1024) ms[i] = midi[b*NFn*Dn + i];
  { int e = tid>>5, d = tid&31; mpw[e*33+d] = mp_w[tid]; }   // 1024 == Dn*Dn
  if (tid < Dn) mpb[tid] = mp_b[tid];
  __syncthreads();
  float* mproj = ws + OFF_MPROJ;
  for (int i=tid;i<NFn*Dn;i+=1024){
    int f = i>>5, e = i&31;
    float a = mpb[e];
    #pragma unroll
    for (int d=0;d<Dn;d++) a += ms[f*32+d]*mpw[e*33+d];
    a = fmaxf(a, 0.0f);
    pj[i] = a;
    mproj[b*NFn*Dn + i] = a;
  }
  __syncthreads();
  int h = tid & 511, fh = tid >> 9;
  float wreg[32];
  #pragma unroll
  for (int d=0;d<32;d++) wreg[d] = wm[h*32+d];
  float* mkey = ws + OFF_MKEY + b*(NFn*Hn);
  for (int ff=0; ff<64; ff++){
    int f = fh*64 + ff;
    float a = 0.f;
    #pragma unroll
    for (int d=0;d<32;d++) a += pj[f*32+d]*wreg[d];
    mkey[f*512 + h] = a;
  }
}

// ---------------- P2: E0[t][j][b] = emb(seq[b,t]) . wih0[j,:300] + biases ----------------
__global__ __launch_bounds__(256) void p2_e0(
    const int* __restrict__ seq, const float* __restrict__ emb,
    const float* __restrict__ wih0, const float* __restrict__ bih0,
    const float* __restrict__ bhh0, float* __restrict__ ws)
{
  __shared__ float elds[Bsz*En];
  __shared__ int sq[Bsz];
  int jblk = blockIdx.x, t = blockIdx.y, tid = threadIdx.x;
  if (tid < Bsz) sq[tid] = seq[tid*Tn + t];
  __syncthreads();
  for (int i=tid; i<Bsz*En; i+=256){
    int bb = i/En, ee = i - bb*En;
    elds[i] = emb[(long)sq[bb]*En + ee];
  }
  __syncthreads();
  int jl = tid >> 5, b = tid & 31;
  const float* er = elds + b*En;
  float* e0 = ws + OFF_E0 + t*(G4*Bsz);
  for (int jj=0;jj<8;jj++){
    int j = jblk*64 + jl*8 + jj;
    const float* wr = wih0 + j*LIN;
    float a0=0,a1=0,a2=0,a3=0;
    for (int e=0;e<En;e+=4){
      float4 w4 = *(const float4*)(wr+e);
      a0 += w4.x*er[e]; a1 += w4.y*er[e+1];
      a2 += w4.z*er[e+2]; a3 += w4.w*er[e+3];
    }
    e0[j*32 + b] = (a0+a1)+(a2+a3) + bih0[j] + bhh0[j];
  }
}

// ---------------- P3: fc_w -> bf16 ----------------
__global__ __launch_bounds__(256) void p3_cvt(
    const float* __restrict__ fcw, float* __restrict__ ws)
{
  u16* dst = (u16*)(ws + OFF_FCWBF);
  int base = (blockIdx.x*256 + threadIdx.x)*8;
  float4 x = *(const float4*)(fcw+base);
  float4 y = *(const float4*)(fcw+base+4);
  short8 p;
  p[0]=(short)f2bf(x.x); p[1]=(short)f2bf(x.y); p[2]=(short)f2bf(x.z); p[3]=(short)f2bf(x.w);
  p[4]=(short)f2bf(y.x); p[5]=(short)f2bf(y.y); p[6]=(short)f2bf(y.z); p[7]=(short)f2bf(y.w);
  *(short8*)(dst+base) = p;
}

// ---------------- P0: zero states, pg0 = E0[0] ----------------
__global__ __launch_bounds__(256) void p0_init(float* __restrict__ ws){
  int idx = blockIdx.x*256 + threadIdx.x;   // grid 256 -> 65536
  if (idx < Hn*Bsz){
    ws[OFF_H1T+idx]=0.f; ws[OFF_C1T+idx]=0.f; ws[OFF_C2T+idx]=0.f;
    ws[OFF_H2A+idx]=0.f; ws[OFF_H2B+idx]=0.f;
  }
  ws[OFF_PG0+idx] = ws[OFF_E0+idx];
}

// ---------------- S1: attention + LSTM0 cell (per-b WG) ----------------
__global__ __launch_bounds__(1024) void s1_step(
    const float* __restrict__ wh, const float* __restrict__ vvec,
    const float* __restrict__ wih0, float* __restrict__ ws,
    const float* __restrict__ h2T, float* __restrict__ out, int t)
{
  __shared__ float h2l[512];
  __shared__ float ql[512];
  __shared__ float qp[512];
  __shared__ float scl[128];
  __shared__ float atl[128];
  __shared__ float ptl[32*33];
  __shared__ float ctxl[32];
  int b = blockIdx.x, tid = threadIdx.x;
  if (tid < 512) h2l[tid] = h2T[tid*32 + b];
  __syncthreads();
  // query[h] = sum_k wh[h,k] * h2_prev[k]  (split-k over 2 halves)
  {
    int h = tid & 511, half = tid >> 9;
    const float* wrow = wh + h*512 + half*256;
    const float* hl = h2l + half*256;
    float a0=0,a1=0,a2=0,a3=0;
    for (int k=0;k<256;k+=4){
      float4 w4 = *(const float4*)(wrow+k);
      a0 += w4.x*hl[k]; a1 += w4.y*hl[k+1]; a2 += w4.z*hl[k+2]; a3 += w4.w*hl[k+3];
    }
    float s = (a0+a1)+(a2+a3);
    if (half) qp[h] = s;
    __syncthreads();
    if (!half) ql[h] = s + qp[h];
  }
  __syncthreads();
  // scores[f] = sum_h v[h]*tanh(q[h]+K[f,h]); 16 waves x 8 f
  {
    int wv = tid >> 6, lane = tid & 63;
    float qq[8], vr[8];
    #pragma unroll
    for (int r=0;r<8;r++){ qq[r]=ql[lane+64*r]; vr[r]=vvec[lane+64*r]; }
    const float* mk = ws + OFF_MKEY + b*(NFn*Hn);
    #pragma unroll 2
    for (int ff=0; ff<8; ff++){
      int f = wv*8+ff;
      const float* mkf = mk + f*512;
      float s = 0.f;
      #pragma unroll
      for (int r=0;r<8;r++) s += vr[r]*ftanh(qq[r] + mkf[lane+64*r]);
      #pragma unroll
      for (int m=1;m<64;m<<=1) s += __shfl_xor(s, m, 64);
      if (lane==0) scl[f] = s;
    }
  }
  __syncthreads();
  // softmax over 128 on wave 0
  if (tid < 64){
    float s0 = scl[tid], s1 = scl[tid+64];
    float mx = fmaxf(s0,s1);
    #pragma unroll
    for (int m=1;m<64;m<<=1) mx = fmaxf(mx, __shfl_xor(mx,m,64));
    float e0 = __expf(s0-mx), e1 = __expf(s1-mx);
    float sm = e0+e1;
    #pragma unroll
    for (int m=1;m<64;m<<=1) sm += __shfl_xor(sm,m,64);
    float inv = frcp(sm);
    float a0=e0*inv, a1=e1*inv;
    atl[tid]=a0; atl[tid+64]=a1;
    float* oa = out + OUT_ATT + b*(Tn*NFn) + t*NFn;
    oa[tid]=a0; oa[tid+64]=a1;
  }
  __syncthreads();
  // ctx[d] = sum_f attn[f]*midi_proj[f,d]
  {
    int d = tid & 31, g = tid >> 5;
    const float* mp = ws + OFF_MPROJ + b*(NFn*Dn);
    float p = 0.f;
    #pragma unroll
    for (int q=0;q<4;q++){ int f = g*4+q; p += atl[f]*mp[f*32+d]; }
    ptl[d*33+g] = p;
  }
  __syncthreads();
  if (tid < 32){
    float s=0.f;
    #pragma unroll
    for (int g=0;g<32;g++) s += ptl[tid*33+g];
    ctxl[tid]=s;
  }
  __syncthreads();
  // h1/c1: g0 = pg0 + wih0[:,300:332].ctx ; cell update
  if (tid < 512){
    int k = tid;
    const float* pg0 = ws + OFF_PG0;
    float gq[4];
    #pragma unroll
    for (int q=0;q<4;q++){
      int j = q*512+k;
      float acc = pg0[j*32+b];
      const float* wr = wih0 + j*LIN + En;
      #pragma unroll
      for (int d=0;d<32;d+=4){
        float4 w4 = *(const float4*)(wr+d);
        acc += w4.x*ctxl[d]+w4.y*ctxl[d+1]+w4.z*ctxl[d+2]+w4.w*ctxl[d+3];
      }
      gq[q]=acc;
    }
    float* c1T = ws + OFF_C1T;
    float* h1T = ws + OFF_H1T;
    float cp = c1T[k*32+b];
    float cn = fsig(gq[1])*cp + fsig(gq[0])*ftanh(gq[2]);
    float hn = fsig(gq[3])*ftanh(cn);
    h1T[k*32+b]=hn; c1T[k*32+b]=cn;
    if (t==63){ out[OUT_HF + b*512 + k]=hn; out[OUT_CF + b*512 + k]=cn; }
  }
}

// ---------------- S2: LSTM1 gates + h2/c2 + pg0 for next step ----------------
__global__ __launch_bounds__(512) void s2_step(
    const float* __restrict__ wih1, const float* __restrict__ whh1,
    const float* __restrict__ whh0, const float* __restrict__ bih1,
    const float* __restrict__ bhh1, float* __restrict__ ws,
    const float* __restrict__ h2r, float* __restrict__ h2w,
    float* __restrict__ out, int t)
{
  __shared__ float gl[2][8][32];
  __shared__ float pl[2][8][32];
  int tid = threadIdx.x, wgb = blockIdx.x;
  int half = tid >> 8;
  int rl = (tid >> 5) & 7;
  int b = tid & 31;
  int kof = rl & 1, q = rl >> 1;
  int k = wgb*2 + kof;
  int row = q*512 + k;
  const float* h1T = ws + OFF_H1T;
  const float* wa = wih1 + row*512 + half*256;
  const float* wb = whh1 + row*512 + half*256;
  const float* wc = whh0 + row*512 + half*256;
  const float* h1p = h1T + (half*256)*32 + b;
  const float* h2p = h2r + (half*256)*32 + b;
  float ga=0.f, gb2=0.f, pa=0.f;
  #pragma unroll 4
  for (int kk=0; kk<256; kk+=4){
    float4 a4 = *(const float4*)(wa+kk);
    float4 b4 = *(const float4*)(wb+kk);
    float4 c4 = *(const float4*)(wc+kk);
    float x0 = h1p[(kk+0)*32], x1 = h1p[(kk+1)*32], x2 = h1p[(kk+2)*32], x3 = h1p[(kk+3)*32];
    float y0 = h2p[(kk+0)*32], y1 = h2p[(kk+1)*32], y2 = h2p[(kk+2)*32], y3 = h2p[(kk+3)*32];
    ga  += a4.x*x0 + a4.y*x1 + a4.z*x2 + a4.w*x3;
    gb2 += b4.x*y0 + b4.y*y1 + b4.z*y2 + b4.w*y3;
    pa  += c4.x*x0 + c4.y*x1 + c4.z*x2 + c4.w*x3;
  }
  gl[half][rl][b] = ga + gb2;
  pl[half][rl][b] = pa;
  __syncthreads();
  if (tid < 256){
    int rl2 = tid >> 5, b2 = tid & 31;
    int kof2 = rl2 & 1, q2 = rl2 >> 1;
    int row2 = q2*512 + wgb*2 + kof2;
    float g = gl[0][rl2][b2] + gl[1][rl2][b2] + bih1[row2] + bhh1[row2];
    gl[0][rl2][b2] = g;
    if (t < 63){
      float pg = pl[0][rl2][b2] + pl[1][rl2][b2] + ws[OFF_E0 + (t+1)*(G4*Bsz) + row2*32 + b2];
      ws[OFF_PG0 + row2*32 + b2] = pg;
    }
  }
  __syncthreads();
  if (tid < 64){
    int kof2 = tid >> 5, b2 = tid & 31;
    int k2 = wgb*2 + kof2;
    float gi = gl[0][(0<<1)|kof2][b2];
    float gf = gl[0][(1<<1)|kof2][b2];
    float gg = gl[0][(2<<1)|kof2][b2];
    float go = gl[0][(3<<1)|kof2][b2];
    float* c2T = ws + OFF_C2T;
    float cp = c2T[k2*32+b2];
    float cn = fsig(gf)*cp + fsig(gi)*ftanh(gg);
    float hn = fsig(go)*ftanh(cn);
    c2T[k2*32+b2]=cn; h2w[k2*32+b2]=hn;
    __hip_bfloat16* hbf = (__hip_bfloat16*)(ws + OFF_HBF);
    hbf[(t*32+b2)*512 + k2] = __float2bfloat16(hn);
    if (t==63){ out[OUT_HF + 16384 + b2*512 + k2]=hn; out[OUT_CF + 16384 + b2*512 + k2]=cn; }
  }
}

// ---------------- FC: logits = h @ fc_w^T + fc_b (bf16 MFMA, 128x128 tile) ----------------
__global__ __launch_bounds__(256) void fc_gemm(
    const float* __restrict__ ws_f, const float* __restrict__ fcb,
    float* __restrict__ out)
{
  const u16* A  = (const u16*)(ws_f + OFF_FCWBF);   // [32000][512] fc_w
  const u16* Bm = (const u16*)(ws_f + OFF_HBF);     // [2048][512] h (bt-major)
  __shared__ u16 Al[128*40];
  __shared__ u16 Bl[128*40];
  int tid = threadIdx.x;
  int v0 = blockIdx.x*128, bt0 = blockIdx.y*128;
  int lane = tid & 63, wv = tid >> 6;
  int wr = wv >> 1, wc = wv & 1;
  f32x4 acc[4][4];
  #pragma unroll
  for (int i=0;i<4;i++)
    #pragma unroll
    for (int j=0;j<4;j++) acc[i][j] = (f32x4){0.f,0.f,0.f,0.f};

  int ar = wr*64 + (lane&15);
  int br = wc*64 + (lane&15);
  int ks = (lane>>4)*8;

  for (int kk=0; kk<512; kk+=32){
    __syncthreads();
    #pragma unroll
    for (int i=0;i<2;i++){
      int ld = tid + 256*i;
      int row = ld >> 2, cs = (ld & 3)*8;
      *(int4*)(&Al[row*40+cs]) = *(const int4*)(A  + (v0+row)*512 + kk + cs);
      *(int4*)(&Bl[row*40+cs]) = *(const int4*)(Bm + (bt0+row)*512 + kk + cs);
    }
    __syncthreads();
    short8 af[4], bf[4];
    #pragma unroll
    for (int m=0;m<4;m++) af[m] = *(const short8*)(&Al[(ar+m*16)*40 + ks]);
    #pragma unroll
    for (int n=0;n<4;n++) bf[n] = *(const short8*)(&Bl[(br+n*16)*40 + ks]);
    #pragma unroll
    for (int m=0;m<4;m++)
      #pragma unroll
      for (int n=0;n<4;n++)
        acc[m][n] = __builtin_amdgcn_mfma_f32_16x16x32_bf16(af[m], bf[n], acc[m][n], 0,0,0);
  }
  int r4 = (lane>>4)*4;
  #pragma unroll
  for (int m=0;m<4;m++){
    int v = v0 + wr*64 + m*16 + r4;
    float4 bias = *(const float4*)(fcb + v);
    #pragma unroll
    for (int n=0;n<4;n++){
      int bt = bt0 + wc*64 + n*16 + (lane&15);
      int b = bt & 31, t = bt >> 5;
      f32x4 a = acc[m][n];
      float4 res = { a[0]+bias.x, a[1]+bias.y, a[2]+bias.z, a[3]+bias.w };
      *(float4*)(out + b*2048000 + t*32000 + v) = res;
    }
  }
}

extern "C" void kernel_launch(void* const* d_in, const int* in_sizes, int n_in,
                              void* d_out, int out_size, void* d_ws, size_t ws_size,
                              hipStream_t stream)
{
  const int*   seq  = (const int*)d_in[0];
  const float* midi = (const float*)d_in[1];
  const float* emb  = (const float*)d_in[2];
  const float* mpw  = (const float*)d_in[3];
  const float* mpb  = (const float*)d_in[4];
  const float* wh   = (const float*)d_in[5];
  const float* wm   = (const float*)d_in[6];
  const float* vv   = (const float*)d_in[7];
  const float* wih0 = (const float*)d_in[8];
  const float* whh0 = (const float*)d_in[9];
  const float* bih0 = (const float*)d_in[10];
  const float* bhh0 = (const float*)d_in[11];
  const float* wih1 = (const float*)d_in[12];
  const float* whh1 = (const float*)d_in[13];
  const float* bih1 = (const float*)d_in[14];
  const float* bhh1 = (const float*)d_in[15];
  const float* fcw  = (const float*)d_in[16];
  const float* fcb  = (const float*)d_in[17];
  float* out = (float*)d_out;
  float* ws  = (float*)d_ws;

  p1_midi<<<32, 1024, 0, stream>>>(midi, mpw, mpb, wm, ws);
  p2_e0<<<dim3(32,64), 256, 0, stream>>>(seq, emb, wih0, bih0, bhh0, ws);
  p3_cvt<<<8000, 256, 0, stream>>>(fcw, ws);
  p0_init<<<256, 256, 0, stream>>>(ws);

  for (int t=0; t<Tn; t++){
    float* h2r = ws + ((t & 1) ? OFF_H2B : OFF_H2A);
    float* h2w = ws + ((t & 1) ? OFF_H2A : OFF_H2B);
    s1_step<<<32, 1024, 0, stream>>>(wh, vv, wih0, ws, h2r, out, t);
    s2_step<<<256, 512, 0, stream>>>(wih1, whh1, whh0, bih1, bhh1, ws, h2r, h2w, out, t);
  }
  fc_gemm<<<dim3(250,16), 256, 0, stream>>>(ws, fcb, out);
}